// Round 4
// baseline (289.327 us; speedup 1.0000x reference)
//
#include <hip/hip_runtime.h>
#include <cstdint>
#include <cstddef>

#define BB 128
#define NN 512
#define EE 512
#define KK 256
#define STR 17  // odd stride: column reads across 64 lanes are 2-way/bank = free

__device__ __forceinline__ float wave_reduce_max(float v) {
#pragma unroll
  for (int off = 32; off >= 1; off >>= 1) v = fmaxf(v, __shfl_xor(v, off, 64));
  return v;
}
__device__ __forceinline__ float wave_reduce_sum(float v) {
#pragma unroll
  for (int off = 32; off >= 1; off >>= 1) v += __shfl_xor(v, off, 64);
  return v;
}

// ---- DPP cross-lane reduces (VALU pipe, not LDS).
template <int CTRL>
__device__ __forceinline__ float dppz(float x) {  // invalid/off lanes contribute 0
  return __int_as_float(__builtin_amdgcn_update_dpp(0, __float_as_int(x), CTRL, 0xf, 0xf, false));
}
template <int CTRL>
__device__ __forceinline__ float dppi(float x) {  // invalid/off lanes contribute x (identity)
  return __int_as_float(__builtin_amdgcn_update_dpp(__float_as_int(x), __float_as_int(x), CTRL, 0xf, 0xf, false));
}
__device__ __forceinline__ float wave_sum64(float x) {  // -> uniform
  x += dppz<0x111>(x); x += dppz<0x112>(x); x += dppz<0x114>(x); x += dppz<0x118>(x);
  x += dppz<0x142>(x); x += dppz<0x143>(x);
  return __int_as_float(__builtin_amdgcn_readlane(__float_as_int(x), 63));
}
__device__ __forceinline__ float wave_max64nn(float x) {  // nonneg inputs
  x = fmaxf(x, dppz<0x111>(x)); x = fmaxf(x, dppz<0x112>(x));
  x = fmaxf(x, dppz<0x114>(x)); x = fmaxf(x, dppz<0x118>(x));
  x = fmaxf(x, dppz<0x142>(x)); x = fmaxf(x, dppz<0x143>(x));
  return __int_as_float(__builtin_amdgcn_readlane(__float_as_int(x), 63));
}
__device__ __forceinline__ float wave_min64(float x) {
  x = fminf(x, dppi<0x111>(x)); x = fminf(x, dppi<0x112>(x));
  x = fminf(x, dppi<0x114>(x)); x = fminf(x, dppi<0x118>(x));
  x = fminf(x, dppi<0x142>(x)); x = fminf(x, dppi<0x143>(x));
  return __int_as_float(__builtin_amdgcn_readlane(__float_as_int(x), 63));
}

__device__ __forceinline__ int cnt4(const float a[4], float p) {
  return __popcll(__ballot(a[0] < p)) + __popcll(__ballot(a[1] < p)) +
         __popcll(__ballot(a[2] < p)) + __popcll(__ballot(a[3] < p));
}

// Lower median (rank 127) of 256 nonnegative values, 4 per lane — single-median
// branchy version (kept for kstage3's 3 medians; tiny share of runtime).
__device__ __forceinline__ float wave_median256_fast(float a0, float a1, float a2, float a3) {
  float S = wave_sum64((a0 + a1) + (a2 + a3));
  float mean = S * 0.00390625f;
  float lo = 0.f, hi = S * 1.0000002f + 1e-37f;
  int c_lo = 0, c_hi = 256;
  float piv = 0.845f * mean;
  float ans = 0.f;
  bool have = false;
#pragma unroll 1
  for (int it = 0; it < 34; ++it) {
    if (!(piv > lo && piv < hi)) piv = 0.5f * (lo + hi);
    int cnt = __popcll(__ballot(a0 < piv)) + __popcll(__ballot(a1 < piv)) +
              __popcll(__ballot(a2 < piv)) + __popcll(__ballot(a3 < piv));
    if (cnt == 128) {
      float m = fmaxf(fmaxf(a0 < piv ? a0 : 0.f, a1 < piv ? a1 : 0.f),
                      fmaxf(a2 < piv ? a2 : 0.f, a3 < piv ? a3 : 0.f));
      ans = wave_max64nn(m); have = true; break;
    }
    if (cnt == 127) {
      float m = fminf(fminf(a0 >= piv ? a0 : 3.4e38f, a1 >= piv ? a1 : 3.4e38f),
                      fminf(a2 >= piv ? a2 : 3.4e38f, a3 >= piv ? a3 : 3.4e38f));
      ans = wave_min64(m); have = true; break;
    }
    if (cnt < 127) { lo = piv; c_lo = cnt; } else { hi = piv; c_hi = cnt; }
    if (it == 0) piv = piv + (127.5f - (float)cnt) * mean * 0.0077f;
    else piv = lo + (hi - lo) * ((127.5f - (float)c_lo) / (float)(c_hi - c_lo));
    if (it >= 10) piv = 0.5f * (lo + hi);
  }
  if (!have) {
    float m = fmaxf(fmaxf(a0 < hi ? a0 : 0.f, a1 < hi ? a1 : 0.f),
                    fmaxf(a2 < hi ? a2 : 0.f, a3 < hi ? a3 : 0.f));
    ans = wave_max64nn(m);
  }
  return ans;
}

// 4 exact lower-medians (rank 127 of 256), interleaved & fully BRANCHLESS:
// loop body is straight-line (cmp/bcnt/select only); exit condition folded to
// flags (c_lo==127 | c_hi==128); the only branch is the uniform all-done check
// once per outer iteration. All exact-answer reduces hoisted after the loop.
// Exactness: c_hi==128 -> ans = max{a < hi}; c_lo==127 -> ans = min{a >= lo};
// 34-iter tie-collapse fallback -> max{a < hi} (same argument as branchy ver).
__device__ __forceinline__ void median4_branchless(const float A[4][4], float ans[4]) {
  float lo[4], hi[4], fclo[4], fchi[4], piv1[4], mean[4];
  bool done[4];
#pragma unroll
  for (int j = 0; j < 4; ++j) {
    float S = wave_sum64((A[j][0] + A[j][1]) + (A[j][2] + A[j][3]));
    mean[j] = S * 0.00390625f;
    lo[j] = 0.f; fclo[j] = 0.f;
    hi[j] = S * 1.0000002f + 1e-37f; fchi[j] = 256.f;
    done[j] = false;
  }
  // it0: model pivot (0.845*mean = half-normal median/mean), prep Newton pivot
#pragma unroll
  for (int j = 0; j < 4; ++j) {
    float piv = 0.845f * mean[j];
    int cnt = cnt4(A[j], piv);
    float cf = (float)cnt;
    bool below = cnt <= 127;
    lo[j] = below ? piv : lo[j];  fclo[j] = below ? cf : fclo[j];
    hi[j] = below ? hi[j] : piv;  fchi[j] = below ? fchi[j] : cf;
    done[j] = (fclo[j] == 127.f) || (fchi[j] == 128.f);
    piv1[j] = piv + (127.5f - cf) * mean[j] * 0.0077f;  // Newton, density 130/mean
  }
  // it1: Newton pivot
#pragma unroll
  for (int j = 0; j < 4; ++j) {
    float piv = piv1[j];
    piv = (piv > lo[j] && piv < hi[j]) ? piv : 0.5f * (lo[j] + hi[j]);
    int cnt = cnt4(A[j], piv);
    float cf = (float)cnt;
    bool b = cnt <= 127, u = !done[j];
    bool bl = b && u, bh = (!b) && u;
    lo[j] = bl ? piv : lo[j];  fclo[j] = bl ? cf : fclo[j];
    hi[j] = bh ? piv : hi[j];  fchi[j] = bh ? cf : fchi[j];
    done[j] = (fclo[j] == 127.f) || (fchi[j] == 128.f);
  }
  // it2..9: bracket secant
#pragma unroll 1
  for (int it = 2; it < 10; ++it) {
    if (done[0] && done[1] && done[2] && done[3]) break;
#pragma unroll
    for (int j = 0; j < 4; ++j) {
      float piv = lo[j] + (hi[j] - lo[j]) * (127.5f - fclo[j]) / (fchi[j] - fclo[j]);
      piv = (piv > lo[j] && piv < hi[j]) ? piv : 0.5f * (lo[j] + hi[j]);
      int cnt = cnt4(A[j], piv);
      float cf = (float)cnt;
      bool b = cnt <= 127, u = !done[j];
      bool bl = b && u, bh = (!b) && u;
      lo[j] = bl ? piv : lo[j];  fclo[j] = bl ? cf : fclo[j];
      hi[j] = bh ? piv : hi[j];  fchi[j] = bh ? cf : fchi[j];
      done[j] = (fclo[j] == 127.f) || (fchi[j] == 128.f);
    }
  }
  // it10..33: midpoint (guaranteed geometric convergence / tie collapse)
#pragma unroll 1
  for (int it = 10; it < 34; ++it) {
    if (done[0] && done[1] && done[2] && done[3]) break;
#pragma unroll
    for (int j = 0; j < 4; ++j) {
      float piv = 0.5f * (lo[j] + hi[j]);
      int cnt = cnt4(A[j], piv);
      float cf = (float)cnt;
      bool b = cnt <= 127, u = !done[j];
      bool bl = b && u, bh = (!b) && u;
      lo[j] = bl ? piv : lo[j];  fclo[j] = bl ? cf : fclo[j];
      hi[j] = bh ? piv : hi[j];  fchi[j] = bh ? cf : fchi[j];
      done[j] = (fclo[j] == 127.f) || (fchi[j] == 128.f);
    }
  }
  // final exact reduces (outside the loop)
#pragma unroll
  for (int j = 0; j < 4; ++j) {
    bool useMin = done[j] && (fclo[j] == 127.f) && (fchi[j] != 128.f);
    if (useMin) {
      float mm = fminf(fminf(A[j][0] >= lo[j] ? A[j][0] : 3.4e38f,
                             A[j][1] >= lo[j] ? A[j][1] : 3.4e38f),
                       fminf(A[j][2] >= lo[j] ? A[j][2] : 3.4e38f,
                             A[j][3] >= lo[j] ? A[j][3] : 3.4e38f));
      ans[j] = wave_min64(mm);
    } else {  // fchi==128 exact, or tie-collapse fallback (exact)
      float mm = fmaxf(fmaxf(A[j][0] < hi[j] ? A[j][0] : 0.f,
                             A[j][1] < hi[j] ? A[j][1] : 0.f),
                       fmaxf(A[j][2] < hi[j] ? A[j][2] : 0.f,
                             A[j][3] < hi[j] ? A[j][3] : 0.f));
      ans[j] = wave_max64nn(mm);
    }
  }
}

// Fused stage: per block (b,g) covering 16 columns — stage the 512x16 errs
// tile in LDS once, 32 chunk-medians (4 per wave, branchless interleaved),
// exp relaxation scalars, head-term partial, partial dots.
__global__ __launch_bounds__(512, 2) void kfused(
    const float* __restrict__ head, const float* __restrict__ errs,
    float* __restrict__ ws_delta, float* __restrict__ ws_htpart,
    float* __restrict__ ws_epart) {
  __shared__ float tile[512 * STR];  // 34816 B
  __shared__ float medbuf[32];       // [chunk*16 + col]
  __shared__ float lambuf[16];
  __shared__ float redm[8];
  const int blk = blockIdx.x;
  const int b = blk >> 5, g = blk & 31;
  const int n0 = g * 16;
  const int tid = threadIdx.x, wave = tid >> 6, lane = tid & 63;

  float m = head[(size_t)b * NN + tid];
  m = wave_reduce_max(m);
  if (lane == 0) redm[wave] = m;

  // stage 512 rows x 16 cols (row segment = 64 B contiguous per 4 lanes)
  const int tr = tid >> 2, tc = (tid & 3) * 4;
  const float* src = errs + (size_t)b * EE * NN + n0 + tc;
#pragma unroll
  for (int i = 0; i < 4; ++i) {
    int row = i * 128 + tr;
    float4 v = *(const float4*)(src + (size_t)row * NN);
    float* dst = &tile[row * STR + tc];
    dst[0] = v.x; dst[1] = v.y; dst[2] = v.z; dst[3] = v.w;
  }
  __syncthreads();

  // 32 medians, 4 per wave, branchless interleaved
  float A[4][4];
#pragma unroll
  for (int j = 0; j < 4; ++j) {
    int p = wave * 4 + j;
    int col = p & 15;
    int rb = (p >> 4) * 256;
    A[j][0] = fabsf(tile[(rb + lane) * STR + col]);
    A[j][1] = fabsf(tile[(rb + lane + 64) * STR + col]);
    A[j][2] = fabsf(tile[(rb + lane + 128) * STR + col]);
    A[j][3] = fabsf(tile[(rb + lane + 192) * STR + col]);
  }
  float ans4[4];
  median4_branchless(A, ans4);
#pragma unroll
  for (int j = 0; j < 4; ++j)
    if (lane == 0) medbuf[wave * 4 + j] = ans4[j];
  __syncthreads();

  // exp relaxation scalars for the 16 columns
  float htp = 0.f;
  if (tid < 16) {
    float hmax = fmaxf(fmaxf(fmaxf(redm[0], redm[1]), fmaxf(redm[2], redm[3])),
                       fmaxf(fmaxf(redm[4], redm[5]), fmaxf(redm[6], redm[7])));
    int n = n0 + tid;
    float l1 = medbuf[tid] + medbuf[16 + tid];
    float th = head[(size_t)b * NN + n] - hmax;
    float lb = th - l1, ub = th + l1;
    float lam, mu, delta;
    if (ub == lb) {
      lam = 0.f; mu = expf(ub); delta = 0.f;
    } else {
      float elb = expf(lb), eub = expf(ub);
      float lam_s = (eub - elb) / (ub - lb + 1e-6f);
      lam = fminf(lam_s, expf(lb + 0.9f));
      float ub0 = (lam > lam_s) ? (elb - lam * lb) : (eub - lam * ub);
      float t = lam * (1.f - logf(lam));
      mu = 0.5f * (t + ub0);
      delta = 0.5f * (ub0 - t);
    }
    lambuf[tid] = lam;
    ws_delta[(size_t)b * NN + n] = delta;
    htp = th * lam + mu;
  }
  if (wave == 0) {
    float s = wave_reduce_sum(htp);  // lanes 16..63 contribute 0
    if (lane == 0) ws_htpart[b * 32 + g] = s;
  }
  __syncthreads();

  // partial dots from the LDS tile (one row per thread)
  float s0 = 0.f;
#pragma unroll
  for (int j = 0; j < 16; ++j) s0 = fmaf(tile[tid * STR + j], lambuf[j], s0);
  ws_epart[((size_t)(b * 32 + g)) * 512 + tid] = s0;
}

// ---- TEMPORARY PROBE 1: staging+dot only (no medians), 1/4 grid (1024 blk).
// Measures the memory/staging floor of kfused in isolation.
__global__ __launch_bounds__(512, 2) void kprobe_stage(
    const float* __restrict__ errs, float* __restrict__ dump) {
  __shared__ float tile[512 * STR];
  const int blk = blockIdx.x;  // 1024 blocks -> b in [0,32), g in [0,32)
  const int b = blk >> 5, g = blk & 31;
  const int n0 = g * 16;
  const int tid = threadIdx.x;
  const int tr = tid >> 2, tc = (tid & 3) * 4;
  const float* src = errs + (size_t)b * EE * NN + n0 + tc;
#pragma unroll
  for (int i = 0; i < 4; ++i) {
    int row = i * 128 + tr;
    float4 v = *(const float4*)(src + (size_t)row * NN);
    float* dst = &tile[row * STR + tc];
    dst[0] = v.x; dst[1] = v.y; dst[2] = v.z; dst[3] = v.w;
  }
  __syncthreads();
  float s0 = 0.f;
#pragma unroll
  for (int j = 0; j < 16; ++j) s0 = fmaf(tile[tid * STR + j], 1.0001f, s0);
  dump[(size_t)blk * 512 + tid] = s0;
}

// ---- TEMPORARY PROBE 2: medians only, synthetic register data, 1/4 grid.
// Same LDS footprint as kfused (declared tile) so occupancy matches.
__global__ __launch_bounds__(512, 2) void kprobe_med(float* __restrict__ dump) {
  __shared__ float tile[512 * STR];
  const int blk = blockIdx.x;  // 1024 blocks
  const int tid = threadIdx.x, wave = tid >> 6, lane = tid & 63;
  tile[tid] = (float)tid;  // pin LDS allocation
  __syncthreads();
  unsigned pin = __float_as_uint(tile[(tid + 257) & 511]);
  float A[4][4];
#pragma unroll
  for (int j = 0; j < 4; ++j)
#pragma unroll
    for (int k = 0; k < 4; ++k) {
      unsigned h = (unsigned)(tid * 2654435761u) ^ (unsigned)(j * 0x9E3779B9u) ^
                   (unsigned)(k * 0x85EBCA6Bu) ^ (unsigned)(blk * 0xC2B2AE35u) ^ pin;
      A[j][k] = (float)(h & 0xFFFFu) * 1e-7f;
    }
  float ans4[4];
  median4_branchless(A, ans4);
  if (lane == 0) {
#pragma unroll
    for (int j = 0; j < 4; ++j) dump[(size_t)blk * 32 + wave * 4 + j] = ans4[j];
  }
}

// cexp part of exp_errs: full dot cauchy_exp[b,j,:] . delta[b,:].
__global__ __launch_bounds__(256) void kcexp(
    const float* __restrict__ cexp, const float* __restrict__ ws_delta,
    float* __restrict__ ws_ee2) {
  const int blk = blockIdx.x;  // 2048 blocks
  const int b = blk >> 4, seg = blk & 15;
  const int wave = threadIdx.x >> 6, lane = threadIdx.x & 63;
  const float* wsrc = ws_delta + (size_t)b * NN;
  float4 wa = *(const float4*)(wsrc + 4 * lane);
  float4 wb = *(const float4*)(wsrc + 256 + 4 * lane);
  const int r0 = seg * 16 + wave * 4;
  const float* base = cexp + (size_t)b * KK * NN;
  float* out = ws_ee2 + (size_t)b * KK;
  float s0, s1, s2, s3;
  {
    const float* rp = base + (size_t)r0 * NN;
    float4 x = *(const float4*)(rp + 4 * lane);
    float4 y = *(const float4*)(rp + 256 + 4 * lane);
    s0 = x.x * wa.x + x.y * wa.y + x.z * wa.z + x.w * wa.w +
         y.x * wb.x + y.y * wb.y + y.z * wb.z + y.w * wb.w;
  }
  {
    const float* rp = base + (size_t)(r0 + 1) * NN;
    float4 x = *(const float4*)(rp + 4 * lane);
    float4 y = *(const float4*)(rp + 256 + 4 * lane);
    s1 = x.x * wa.x + x.y * wa.y + x.z * wa.z + x.w * wa.w +
         y.x * wb.x + y.y * wb.y + y.z * wb.z + y.w * wb.w;
  }
  {
    const float* rp = base + (size_t)(r0 + 2) * NN;
    float4 x = *(const float4*)(rp + 4 * lane);
    float4 y = *(const float4*)(rp + 256 + 4 * lane);
    s2 = x.x * wa.x + x.y * wa.y + x.z * wa.z + x.w * wa.w +
         y.x * wb.x + y.y * wb.y + y.z * wb.z + y.w * wb.w;
  }
  {
    const float* rp = base + (size_t)(r0 + 3) * NN;
    float4 x = *(const float4*)(rp + 4 * lane);
    float4 y = *(const float4*)(rp + 256 + 4 * lane);
    s3 = x.x * wa.x + x.y * wa.y + x.z * wa.z + x.w * wa.w +
         y.x * wb.x + y.y * wb.y + y.z * wb.z + y.w * wb.w;
  }
  s0 = wave_sum64(s0);
  s1 = wave_sum64(s1);
  s2 = wave_sum64(s2);
  s3 = wave_sum64(s3);
  if (lane == 0) {
    out[r0] = s0; out[r0 + 1] = s1; out[r0 + 2] = s2; out[r0 + 3] = s3;
  }
}

// Stage 3: per b — combine 32 partials into exp_errs[0:512], append cexp dots,
// exp_head sum from htparts, 3 medians of 256, log relaxation, outputs.
__global__ __launch_bounds__(256) void kstage3(
    const float* __restrict__ head, const float* __restrict__ clog,
    const float* __restrict__ ws_htpart, const float* __restrict__ ws_epart,
    const float* __restrict__ ws_ee2, float* __restrict__ out) {
  __shared__ float eb[768];
  __shared__ float redm[4];
  __shared__ float meds[3];
  __shared__ float sc[2];
  __shared__ float ehsh;
  const int b = blockIdx.x;
  const int tid = threadIdx.x, wave = tid >> 6, lane = tid & 63;

  float m = fmaxf(head[(size_t)b * NN + tid], head[(size_t)b * NN + 256 + tid]);
  m = wave_reduce_max(m);
  if (lane == 0) redm[wave] = m;

  float acc0 = 0.f, acc1 = 0.f;
  const float* pp = ws_epart + (size_t)b * 32 * 512;
#pragma unroll
  for (int g = 0; g < 32; ++g) {
    acc0 += pp[g * 512 + tid];
    acc1 += pp[g * 512 + 256 + tid];
  }
  eb[tid] = acc0;
  eb[tid + 256] = acc1;
  eb[tid + 512] = ws_ee2[(size_t)b * KK + tid];
  __syncthreads();

  if (wave < 3) {
    const float* p = eb + wave * 256;
    float a0 = fabsf(p[lane]), a1 = fabsf(p[lane + 64]);
    float a2 = fabsf(p[lane + 128]), a3 = fabsf(p[lane + 192]);
    float med = wave_median256_fast(a0, a1, a2, a3);
    if (lane == 0) meds[wave] = med;
  } else {
    float v = (lane < 32) ? ws_htpart[b * 32 + lane] : 0.f;
    v = wave_reduce_sum(v);
    if (lane == 0) ehsh = v;
  }
  __syncthreads();

  if (tid == 0) {
    float hmax = fmaxf(fmaxf(redm[0], redm[1]), fmaxf(redm[2], redm[3]));
    float eh = ehsh;
    float l1 = meds[0] + meds[1] + meds[2];
    float lb = eh - l1, ub = eh + l1;
    float lam, mu, delta;
    if (ub == lb) {
      lam = 0.f; mu = logf(ub); delta = 0.f;
    } else {
      float llb = logf(lb + 1e-6f);
      float lam_s = (logf(ub) - llb) / (ub - lb + 1e-6f);
      lam = lam_s;
      float lb0 = llb - lb * lam;  // reference's where(lam<lam_s,...) always takes else
      float t = -logf(lam) - 1.f;
      mu = 0.5f * (t + lb0);
      delta = 0.5f * (t - lb0);
    }
    sc[0] = lam; sc[1] = delta;
    out[b] = eh * lam + mu + hmax;
  }
  __syncthreads();
  float lam = sc[0], delta = sc[1];
  float* ob = out + BB + (size_t)b * 1024;
  ob[tid] = eb[tid] * lam;
  ob[tid + 256] = eb[tid + 256] * lam;
  ob[tid + 512] = eb[tid + 512] * lam;
  ob[tid + 768] = delta * clog[(size_t)b * KK + tid];
}

extern "C" void kernel_launch(void* const* d_in, const int* in_sizes, int n_in,
                              void* d_out, int out_size, void* d_ws, size_t ws_size,
                              hipStream_t stream) {
  const float* head = (const float*)d_in[0];   // (128, 512)
  const float* errs = (const float*)d_in[1];   // (65536, 512)
  const float* cexp = (const float*)d_in[2];   // (128, 256, 512)
  const float* clog = (const float*)d_in[3];   // (128, 256)
  float* out = (float*)d_out;                  // 128 + 131072 floats

  float* ws = (float*)d_ws;
  float* ws_delta = ws;                        // 65536
  float* ws_htpart = ws_delta + BB * NN;       // 4096
  float* ws_ee2 = ws_htpart + BB * 32;         // 32768
  float* ws_epart = ws_ee2 + BB * KK;          // 128*32*512 = 2097152
  float* ws_probe1 = ws_epart + 2097152;       // 1024*512 (scratch)
  float* ws_probe2 = ws_probe1 + 524288;       // 1024*32  (scratch)

  hipLaunchKernelGGL(kfused, dim3(BB * 32), dim3(512), 0, stream,
                     head, errs, ws_delta, ws_htpart, ws_epart);
  hipLaunchKernelGGL(kcexp, dim3(BB * 16), dim3(256), 0, stream,
                     cexp, ws_delta, ws_ee2);
  hipLaunchKernelGGL(kstage3, dim3(BB), dim3(256), 0, stream,
                     head, clog, ws_htpart, ws_epart, ws_ee2, out);
  // TEMPORARY instrumentation (phase split; deleted next round): 1/4-grid
  // probes run after the real pipeline, writing to dead ws scratch.
  hipLaunchKernelGGL(kprobe_stage, dim3(1024), dim3(512), 0, stream,
                     errs, ws_probe1);
  hipLaunchKernelGGL(kprobe_med, dim3(1024), dim3(512), 0, stream,
                     ws_probe2);
}